// Round 9
// baseline (372.475 us; speedup 1.0000x reference)
//
#include <hip/hip_runtime.h>

// Round 17: FFN1 moved to a 256^2 8-wave phase-split GEMM (k_g256, T3/T5-class;
// m201 template geometry): 512 thr, 128KB LDS = 2 dbuf x 4 half-tiles
// (A0,A1,B0,B1 @ 128x64), 4 phases/K-tile, each phase = {stage half-p of
// tile T+1 into dead dbuf, 12 ds_read_b128, 16 MFMA quadrant w/ setprio,
// barrier}; tile boundary = vmcnt(0)+barrier (stages overlap a full tile of
// compute vs the old issue-then-drain). Reuses the proven &7-rotation swizzle
// (0 bank conflicts) + gl_lds w=16. FFN1 grid 16x16 = 256 blocks = 1/CU.
// All other kernels unchanged from R16. FFN1 K-accumulation order identical.

typedef unsigned short u16;
typedef __attribute__((ext_vector_type(8))) short bvec8;   // 8 bf16 (4 VGPRs)
typedef __attribute__((ext_vector_type(4))) float fvec4;
typedef __attribute__((ext_vector_type(4))) unsigned uvec4;

#define MFMA16(a, b, c) __builtin_amdgcn_mfma_f32_16x16x32_bf16((a), (b), (c), 0, 0, 0)

__device__ __forceinline__ u16 f2b(float f) {
  union { float f; unsigned u; } x; x.f = f;
  unsigned u = x.u;
  return (u16)((u + 0x7FFFu + ((u >> 16) & 1u)) >> 16);  // RNE
}
// packed f32x2 -> bf16x2 (RNE), dst.lo = lo, dst.hi = hi
__device__ __forceinline__ unsigned cvtpk(float lo, float hi) {
  unsigned r;
  asm("v_cvt_pk_bf16_f32 %0, %1, %2" : "=v"(r) : "v"(lo), "v"(hi));
  return r;
}
// in-place cross-lane swaps (gfx950): 32 = swap halves across lane^32 axis,
// 16 = swap odd 16-rows of a with even 16-rows of b (lane^16 axis)
#define PLSWAP32(a, b) asm("v_permlane32_swap_b32 %0, %1" : "+v"(a), "+v"(b))
#define PLSWAP16(a, b) asm("v_permlane16_swap_b32 %0, %1" : "+v"(a), "+v"(b))

// async global->LDS, 16B/lane; LDS dest = wave-uniform base + lane*16
__device__ __forceinline__ void gl_lds16(const u16* g, u16* lds) {
  __builtin_amdgcn_global_load_lds(
      (const __attribute__((address_space(1))) void*)g,
      (__attribute__((address_space(3))) void*)lds, 16, 0, 0);
}

// ------- merged prep: fp32->bf16 converts (blocks 0..8191) + all weight
// ------- transposes W[K][N] -> WT[N][K] bf16 (blocks 8192..20479) ----------
__global__ __launch_bounds__(256) void k_pre(
    const float* __restrict__ tgt, const float* __restrict__ mem,
    const float* __restrict__ wq, const float* __restrict__ wk,
    const float* __restrict__ wv, const float* __restrict__ wo,
    const float* __restrict__ w1, const float* __restrict__ w2,
    u16* __restrict__ tgt_b, u16* __restrict__ mem_b,
    u16* __restrict__ wqT, u16* __restrict__ wkvT, u16* __restrict__ woT,
    u16* __restrict__ w1T, u16* __restrict__ w2T) {
  __shared__ float t[32][33];
  int bb = blockIdx.x;
  if (bb < 8192) {  // activation converts
    const float* in = (bb < 4096) ? tgt : mem;
    u16* outp = (bb < 4096) ? tgt_b : mem_b;
    int i = (bb & 4095) * 256 + threadIdx.x;
    float4 v = ((const float4*)in)[i];
    ushort4 o;
    o.x = f2b(v.x); o.y = f2b(v.y); o.z = f2b(v.z); o.w = f2b(v.w);
    ((ushort4*)outp)[i] = o;
    return;
  }
  int b = bb - 8192;
  const float* W; u16* WT; int K, N, bx, by;
  if (b < 4096) {            // wq/wk/wv/wo: 1024x1024, 1024 tiles each
    int m = b >> 10, tt = b & 1023;
    bx = tt & 31; by = tt >> 5; K = 1024; N = 1024;
    W = (m == 0) ? wq : (m == 1) ? wk : (m == 2) ? wv : wo;
    WT = (m == 0) ? wqT : (m == 1) ? wkvT : (m == 2) ? wkvT + 1024 * 1024 : woT;
  } else if (b < 8192) {     // w1: K=1024, N=4096
    int tt = b - 4096; bx = tt & 127; by = tt >> 7; K = 1024; N = 4096;
    W = w1; WT = w1T;
  } else {                   // w2: K=4096, N=1024
    int tt = b - 8192; bx = tt & 31; by = tt >> 5; K = 4096; N = 1024;
    W = w2; WT = w2T;
  }
  int tx = threadIdx.x & 31, ty = threadIdx.x >> 5;
  int n0 = bx * 32, k0 = by * 32;
#pragma unroll
  for (int i = 0; i < 4; i++)
    t[ty + i * 8][tx] = W[(size_t)(k0 + ty + i * 8) * N + n0 + tx];
  __syncthreads();
#pragma unroll
  for (int i = 0; i < 4; i++)
    WT[(size_t)(n0 + ty + i * 8) * K + k0 + tx] = f2b(t[tx][ty + i * 8]);
}

// ------- merged Q-proj + KV-proj, 128x128 tiles, BK=64, V-transpose fused ----
__global__ __launch_bounds__(256, 4) void k_qkv(
    const u16* __restrict__ tgt_b, const u16* __restrict__ mem_b,
    const u16* __restrict__ wqT, const u16* __restrict__ wkvT,
    const float* __restrict__ bq, const float* __restrict__ bk,
    const float* __restrict__ bv,
    u16* __restrict__ Qb, u16* __restrict__ Kb, u16* __restrict__ Vtb) {
  __shared__ u16 S[256 * 64];
  const int tid = threadIdx.x, w = tid >> 6, lane = tid & 63;
  const int q = lane >> 4, l = lane & 15;
  const bool isQ = blockIdx.x < 256;
  const int pq = isQ ? blockIdx.x : blockIdx.x - 256;
  const int lx = (pq >> 3) & (isQ ? 7 : 15);
  const int ly = (pq & 7) + ((pq >> (isQ ? 6 : 7)) << 3);
  const int m0 = ly * 128, n0 = lx * 128;
  const u16* A = isQ ? tgt_b : mem_b;
  const u16* BT = isQ ? wqT : wkvT;
  const int wm = (w >> 1) * 64, wn = (w & 1) * 64;
  const int rowin = lane >> 3, grp = lane & 7;
  const int gcol = ((grp + rowin) & 7) * 8;
  const int kc0 = ((q + 8 - (l & 7)) & 7) * 8;
  const int kc1 = ((q + 12 - (l & 7)) & 7) * 8;
  const u16* gp[8];
  u16* lp[8];
#pragma unroll
  for (int c = 0; c < 8; c++) {
    int r0 = (w * 8 + c) * 8;
    gp[c] = (r0 < 128) ? A + (size_t)(m0 + r0 + rowin) * 1024 + gcol
                       : BT + (size_t)(n0 + r0 - 128 + rowin) * 1024 + gcol;
    lp[c] = &S[r0 * 64];
  }
  fvec4 acc[4][4] = {};
#pragma unroll 1
  for (int k0 = 0; k0 < 1024; k0 += 64) {
#pragma unroll
    for (int c = 0; c < 8; c++) gl_lds16(gp[c] + k0, lp[c]);
    __syncthreads();
#pragma unroll
    for (int kh = 0; kh < 2; kh++) {
      const int kc = kh ? kc1 : kc0;
      bvec8 af[4], bf[4];
#pragma unroll
      for (int i = 0; i < 4; i++) {
        af[i] = *(const bvec8*)&S[(wm + 16 * i + l) * 64 + kc];
        bf[i] = *(const bvec8*)&S[(128 + wn + 16 * i + l) * 64 + kc];
      }
#pragma unroll
      for (int i = 0; i < 4; i++)
#pragma unroll
        for (int j = 0; j < 4; j++)
          acc[i][j] = MFMA16(af[i], bf[j], acc[i][j]);
    }
    __syncthreads();
  }
#pragma unroll
  for (int mi = 0; mi < 4; mi++)
#pragma unroll
    for (int ni = 0; ni < 4; ni++) {
      int row = m0 + wm + mi * 16 + q * 4;
      int col = n0 + wn + ni * 16 + l;
      if (isQ) {
        float bvv = bq[col];
#pragma unroll
        for (int r = 0; r < 4; r++)
          Qb[(size_t)(row + r) * 1024 + col] = f2b((acc[mi][ni][r] + bvv) * 0.125f);
      } else if (col < 1024) {
        float bvv = bk[col];
#pragma unroll
        for (int r = 0; r < 4; r++)
          Kb[(size_t)(row + r) * 1024 + col] = f2b(acc[mi][ni][r] + bvv);
      } else {
        int vcol = col - 1024;
        float bvv = bv[vcol];
        int b = row >> 11, s = row & 2047;
        int h = vcol >> 6, d = vcol & 63;
        ushort4 o;
        o.x = f2b(acc[mi][ni][0] + bvv);
        o.y = f2b(acc[mi][ni][1] + bvv);
        o.z = f2b(acc[mi][ni][2] + bvv);
        o.w = f2b(acc[mi][ni][3] + bvv);
        *(ushort4*)&Vtb[((size_t)(b * 16 + h) * 64 + d) * 2048 + s] = o;
      }
    }
}

// ---------------- templated MFMA GEMM (128-class): C = A @ BT^T -------------
template <int TM, int TN>
__global__ __launch_bounds__(256, 4) void k_gemm(
    const u16* __restrict__ A, const u16* __restrict__ BT,
    const float* __restrict__ bias, const float* __restrict__ resid,
    float* __restrict__ outF, u16* __restrict__ outB,
    int M, int N, int Kstride, int Klen, float scale, int flags) {
  constexpr int WM = TM / 2, WN = TN / 2;
  constexpr int MI = WM / 16, NI = WN / 16;
  constexpr int NCALL = (TM + TN) / 32;
  __shared__ u16 S[(TM + TN) * 64];
  const int tid = threadIdx.x, w = tid >> 6, lane = tid & 63;
  const int q = lane >> 4, l = lane & 15;
  const int nx = gridDim.x, nyh = gridDim.y >> 3;
  const int p = blockIdx.x + nx * (blockIdx.y + gridDim.y * blockIdx.z);
  const int q8 = p >> 3;
  const int lx = q8 & (nx - 1);
  const int t = q8 >> __builtin_ctz(nx);
  const int ly = (p & 7) + ((t & (nyh - 1)) << 3);
  const int lz = t >> __builtin_ctz(nyh);
  const int m0 = ly * TM, n0 = lx * TN;
  const int kbeg = lz * Klen;
  const int wm = (w >> 1) * WM, wn = (w & 1) * WN;
  const int rowin = lane >> 3, grp = lane & 7;
  const int gcol = ((grp + rowin) & 7) * 8;
  const int kc0 = ((q + 8 - (l & 7)) & 7) * 8;
  const int kc1 = ((q + 12 - (l & 7)) & 7) * 8;
  const u16* gp[NCALL];
  u16* lp[NCALL];
#pragma unroll
  for (int c = 0; c < NCALL; c++) {
    int r0 = (w * NCALL + c) * 8;
    gp[c] = (r0 < TM) ? A + (size_t)(m0 + r0 + rowin) * Kstride + kbeg + gcol
                      : BT + (size_t)(n0 + r0 - TM + rowin) * Kstride + kbeg + gcol;
    lp[c] = &S[r0 * 64];
  }
  fvec4 acc[MI][NI] = {};
#pragma unroll 1
  for (int k0 = 0; k0 < Klen; k0 += 64) {
#pragma unroll
    for (int c = 0; c < NCALL; c++) gl_lds16(gp[c] + k0, lp[c]);
    __syncthreads();
#pragma unroll
    for (int kh = 0; kh < 2; kh++) {
      const int kc = kh ? kc1 : kc0;
      bvec8 af[MI], bf[NI];
#pragma unroll
      for (int i = 0; i < MI; i++)
        af[i] = *(const bvec8*)&S[(wm + 16 * i + l) * 64 + kc];
#pragma unroll
      for (int j = 0; j < NI; j++)
        bf[j] = *(const bvec8*)&S[(TM + wn + 16 * j + l) * 64 + kc];
#pragma unroll
      for (int i = 0; i < MI; i++)
#pragma unroll
        for (int j = 0; j < NI; j++)
          acc[i][j] = MFMA16(af[i], bf[j], acc[i][j]);
    }
    __syncthreads();
  }
  if (flags & 16) {
    float* po = outF + (size_t)lz * M * N;
#pragma unroll
    for (int mi = 0; mi < MI; mi++)
#pragma unroll
      for (int ni = 0; ni < NI; ni++) {
        int row = m0 + wm + mi * 16 + q * 4;
        int col = n0 + wn + ni * 16 + l;
#pragma unroll
        for (int r = 0; r < 4; r++)
          po[(size_t)(row + r) * N + col] = acc[mi][ni][r];
      }
    return;
  }
#pragma unroll
  for (int mi = 0; mi < MI; mi++)
#pragma unroll
    for (int ni = 0; ni < NI; ni++) {
      int row = m0 + wm + mi * 16 + q * 4;
      int col = n0 + wn + ni * 16 + l;
      float bvv = bias[col];
#pragma unroll
      for (int r = 0; r < 4; r++) {
        float v = (acc[mi][ni][r] + bvv) * scale;
        if (flags & 1) v = fmaxf(v, 0.0f);
        size_t idx = (size_t)(row + r) * N + col;
        if (flags & 8) v += resid[idx];
        if (flags & 2) outB[idx] = f2b(v);
        if (flags & 4) outF[idx] = v;
      }
    }
}

// ------------- 256^2 phase-split GEMM (8 waves, 512 thr, 128KB LDS) ---------
// 2 dbuf x 4 half-tiles {A0,A1,B0,B1} of [128 rows][64 k], &7-rotation
// swizzle (0 bank conflicts). Waves 2M x 4N: wave C = 128x64 (acc 8x4 frags).
// Per K-tile: 4 phases; phase p = {stage half p of tile T+1 into dbuf^1
// (2 gl_lds), 12 ds_read_b128, 16 MFMA quadrant (i-half p>>1, j-pair p&1)
// under setprio, barrier}. Tile boundary: vmcnt(0) + barrier (stages had a
// full tile of compute to land). flags: 1=relu, 2=bf16 outB, 4=fp32 outF,
// 16=raw split-K partial (outF + lz*M*N).
__global__ __launch_bounds__(512, 2) void k_g256(
    const u16* __restrict__ A, const u16* __restrict__ BT,
    const float* __restrict__ bias,
    float* __restrict__ outF, u16* __restrict__ outB,
    int M, int N, int Kstride, int Klen, int flags) {
  __shared__ u16 S[2][4][128 * 64];   // 128 KB
  const int tid = threadIdx.x, w = tid >> 6, lane = tid & 63;
  const int q = lane >> 4, l = lane & 15;
  // XCD-locality remap (bijective for pow2 dims, ny>=8): p%8 == ly&7
  const int nx = gridDim.x, nyh = gridDim.y >> 3;
  const int p = blockIdx.x + nx * (blockIdx.y + gridDim.y * blockIdx.z);
  const int q8 = p >> 3;
  const int lx = q8 & (nx - 1);
  const int tq = q8 >> __builtin_ctz(nx);
  const int ly = (p & 7) + ((tq & (nyh - 1)) << 3);
  const int lz = tq >> __builtin_ctz(nyh);
  const int m0 = ly * 256, n0 = lx * 256;
  const int kbeg = lz * Klen;
  const int wm = (w >> 2) * 128, wn = (w & 3) * 64;
  const int ha = w >> 2;                 // wave's A half (0/1)
  const int hb = 2 + ((w & 3) >> 1);     // wave's B half (2/3)
  const int rb0 = (w & 1) * 64;          // b-frag local row base within half
  const int rt = tid >> 3, grp = tid & 7;
  const int kc0 = ((q + 8 - (l & 7)) & 7) * 8;
  const int kc1 = ((q + 12 - (l & 7)) & 7) * 8;
  const int NT = Klen >> 6;
  const u16* hbase[4] = {A + (size_t)m0 * Kstride,
                         A + (size_t)(m0 + 128) * Kstride,
                         BT + (size_t)n0 * Kstride,
                         BT + (size_t)(n0 + 128) * Kstride};
  auto stageHalf = [&](int d, int h, int T) {
#pragma unroll
    for (int c = 0; c < 2; c++) {
      int r = c * 64 + rt;  // 0..127; lane's row = c*64 + w*8 + (lane>>3)
      int gc = kbeg + T * 64 + (((grp + r) & 7) << 3);
      gl_lds16(hbase[h] + (size_t)r * Kstride + gc,
               &S[d][h][(c * 64 + w * 8) * 64]);
    }
  };
  fvec4 acc[8][4] = {};
  stageHalf(0, 0, 0); stageHalf(0, 1, 0);
  stageHalf(0, 2, 0); stageHalf(0, 3, 0);
  asm volatile("s_waitcnt vmcnt(0)" ::: "memory");
  __builtin_amdgcn_s_barrier();
  int d = 0;
#pragma unroll 1
  for (int T = 0; T < NT; ++T) {
#pragma unroll
    for (int ph = 0; ph < 4; ++ph) {
      if (T + 1 < NT) stageHalf(d ^ 1, ph, T + 1);  // lands by next boundary
      const int i0 = (ph >> 1) * 4, j0 = (ph & 1) * 2;
      const u16* SA = S[d][ha];
      const u16* SB = S[d][hb];
      bvec8 af[4][2], bf[2][2];
#pragma unroll
      for (int i = 0; i < 4; i++) {
        af[i][0] = *(const bvec8*)&SA[(16 * (i0 + i) + l) * 64 + kc0];
        af[i][1] = *(const bvec8*)&SA[(16 * (i0 + i) + l) * 64 + kc1];
      }
#pragma unroll
      for (int j = 0; j < 2; j++) {
        bf[j][0] = *(const bvec8*)&SB[(rb0 + 16 * (j0 + j) + l) * 64 + kc0];
        bf[j][1] = *(const bvec8*)&SB[(rb0 + 16 * (j0 + j) + l) * 64 + kc1];
      }
      __builtin_amdgcn_s_setprio(1);
#pragma unroll
      for (int i = 0; i < 4; i++)
#pragma unroll
        for (int j = 0; j < 2; j++) {
          acc[i0 + i][j0 + j] = MFMA16(af[i][0], bf[j][0], acc[i0 + i][j0 + j]);
          acc[i0 + i][j0 + j] = MFMA16(af[i][1], bf[j][1], acc[i0 + i][j0 + j]);
        }
      __builtin_amdgcn_s_setprio(0);
      if (ph < 3) __builtin_amdgcn_s_barrier();
    }
    asm volatile("s_waitcnt vmcnt(0)" ::: "memory");
    __builtin_amdgcn_s_barrier();
    d ^= 1;
  }
  if (flags & 16) {
    float* po = outF + (size_t)lz * M * N;
#pragma unroll
    for (int i = 0; i < 8; i++)
#pragma unroll
      for (int j = 0; j < 4; j++) {
        int row = m0 + wm + 16 * i + q * 4;
        int col = n0 + wn + 16 * j + l;
#pragma unroll
        for (int r = 0; r < 4; r++)
          po[(size_t)(row + r) * N + col] = acc[i][j][r];
      }
    return;
  }
#pragma unroll
  for (int i = 0; i < 8; i++)
#pragma unroll
    for (int j = 0; j < 4; j++) {
      int row = m0 + wm + 16 * i + q * 4;
      int col = n0 + wn + 16 * j + l;
      float bvv = bias[col];
#pragma unroll
      for (int r = 0; r < 4; r++) {
        float v = acc[i][j][r] + bvv;
        if (flags & 1) v = fmaxf(v, 0.0f);
        size_t idx = (size_t)(row + r) * N + col;
        if (flags & 2) outB[idx] = f2b(v);
        if (flags & 4) outF[idx] = v;
      }
    }
}

// ---------------- block-cooperative no-max flash attention, t-split ----------
__global__ __launch_bounds__(256, 4) void k_attn(
    const u16* __restrict__ Q, const u16* __restrict__ Kb,
    const u16* __restrict__ Vt, u16* __restrict__ ctx) {
  __shared__ u16 Ks[2][64 * 64];
  __shared__ u16 Vs[2][64 * 64];
  const int tid = threadIdx.x, w = tid >> 6, lane = tid & 63;
  const int q = lane >> 4, l = lane & 15;
  const int bx = blockIdx.x;
  const int blk = (bx & 7) * 128 + (bx >> 3);
  const int bh = blk >> 5, tb = blk & 31;
  const int b = bh >> 4, h = bh & 15;
  const int t0 = tb * 64 + w * 16;
  const u16* Qp = Q + (size_t)(b * 2048 + t0) * 1024 + h * 64;
  const u16* Kp = Kb + (size_t)(b * 2048) * 1024 + h * 64;
  const u16* Vp = Vt + (size_t)bh * 64 * 2048;
  const int rowin = lane >> 3, grp = lane & 7;
  const int gcol = ((grp + rowin) & 7) * 8;
  const int kc0 = ((q + 8 - (l & 7)) & 7) * 8;
  const int kc1 = ((q + 12 - (l & 7)) & 7) * 8;
  bvec8 aQ[2];
#pragma unroll
  for (int kh = 0; kh < 2; kh++)
    aQ[kh] = *(const bvec8*)&Qp[(size_t)l * 1024 + kh * 32 + q * 8];
  const short oneb = (short)0x3F80;
  const bvec8 aOne = {oneb, oneb, oneb, oneb, oneb, oneb, oneb, oneb};
  fvec4 o[4] = {};
  fvec4 lacc = {};
  auto stage = [&](int bb, int sv) {
    gl_lds16(Kp + (size_t)(sv + w * 8 + rowin) * 1024 + gcol, &Ks[bb][(w * 8) * 64]);
    gl_lds16(Kp + (size_t)(sv + 32 + w * 8 + rowin) * 1024 + gcol, &Ks[bb][(32 + w * 8) * 64]);
    gl_lds16(Vp + (size_t)(w * 8 + rowin) * 2048 + sv + gcol, &Vs[bb][(w * 8) * 64]);
    gl_lds16(Vp + (size_t)(32 + w * 8 + rowin) * 2048 + sv + gcol, &Vs[bb][(32 + w * 8) * 64]);
  };
  stage(0, 0);
  int cur = 0;
#pragma unroll 1
  for (int s0 = 0; s0 < 2048; s0 += 64) {
    __syncthreads();
    if (s0 + 64 < 2048) stage(cur ^ 1, s0 + 64);
    const u16* KsC = Ks[cur];
    const u16* VsC = Vs[cur];
    unsigned pw[4][2];
    __builtin_amdgcn_s_setprio(1);
#pragma unroll
    for (int ss = 0; ss < 4; ss++) {
      const int ro = (ss * 16 + l) * 64;
      bvec8 kf0 = *(const bvec8*)&KsC[ro + kc0];
      bvec8 kf1 = *(const bvec8*)&KsC[ro + kc1];
      fvec4 sc = {0.f, 0.f, 0.f, 0.f};
      sc = MFMA16(kf0, aQ[0], sc);
      sc = MFMA16(kf1, aQ[1], sc);
      float p0 = __expf(sc[0]), p1 = __expf(sc[1]);
      float p2 = __expf(sc[2]), p3 = __expf(sc[3]);
      pw[ss][0] = cvtpk(p0, p1);
      pw[ss][1] = cvtpk(p2, p3);
    }
    __builtin_amdgcn_s_setprio(0);
#pragma unroll
    for (int b4 = 0; b4 < 2; b4++)
#pragma unroll
      for (int r2 = 0; r2 < 2; r2++) {
        PLSWAP32(pw[2 * b4][r2], pw[2 * b4 + 1][r2]);
        PLSWAP16(pw[2 * b4][r2], pw[2 * b4 + 1][r2]);
      }
    bvec8 bP[2];
#pragma unroll
    for (int kh = 0; kh < 2; kh++) {
      uvec4 t = {pw[2 * kh][0], pw[2 * kh][1],
                 pw[2 * kh + 1][0], pw[2 * kh + 1][1]};
      bP[kh] = __builtin_bit_cast(bvec8, t);
    }
    bvec8 bV[4][2];
#pragma unroll
    for (int dt = 0; dt < 4; dt++) {
      const int ro = (dt * 16 + l) * 64;
      bV[dt][0] = *(const bvec8*)&VsC[ro + kc0];
      bV[dt][1] = *(const bvec8*)&VsC[ro + kc1];
    }
    __builtin_amdgcn_s_setprio(1);
#pragma unroll
    for (int dt = 0; dt < 4; dt++) {
      o[dt] = MFMA16(bV[dt][0], bP[0], o[dt]);
      o[dt] = MFMA16(bV[dt][1], bP[1], o[dt]);
    }
    lacc = MFMA16(aOne, bP[0], lacc);
    lacc = MFMA16(aOne, bP[1], lacc);
    __builtin_amdgcn_s_setprio(0);
    cur ^= 1;
  }
  const float inv = 1.0f / lacc[0];
  u16* cp = ctx + (size_t)(b * 2048 + t0 + l) * 1024 + h * 64;
#pragma unroll
  for (int dt = 0; dt < 4; dt++) {
    ushort4 o4;
    o4.x = f2b(o[dt][0] * inv);
    o4.y = f2b(o[dt][1] * inv);
    o4.z = f2b(o[dt][2] * inv);
    o4.w = f2b(o[dt][3] * inv);
    *(ushort4*)&cp[dt * 16 + q * 4] = o4;
  }
}

// ---- LayerNorm over dim 1024, fused split-K combine: y = Σparts+bias+res ----
__global__ __launch_bounds__(256) void k_lnp(
    const float* __restrict__ parts, int nparts,
    const float* __restrict__ bias, const float* __restrict__ resid,
    const float* __restrict__ g, const float* __restrict__ be,
    float* __restrict__ xf, u16* __restrict__ xb) {
  __shared__ float sm[8];
  int row = blockIdx.x, tid = threadIdx.x;
  size_t base = (size_t)row * 1024;
  const size_t pstride = (size_t)4096 * 1024;
  float v[4], s = 0.f, ss = 0.f;
#pragma unroll
  for (int j = 0; j < 4; j++) {
    int c = tid + j * 256;
    float acc = bias[c] + resid[base + c];
    for (int z = 0; z < nparts; z++) acc += parts[z * pstride + base + c];
    v[j] = acc;
    s += acc; ss += acc * acc;
  }
#pragma unroll
  for (int off = 32; off; off >>= 1) {
    s += __shfl_down(s, off, 64);
    ss += __shfl_down(ss, off, 64);
  }
  int w = tid >> 6;
  if ((tid & 63) == 0) { sm[w] = s; sm[4 + w] = ss; }
  __syncthreads();
  float S = sm[0] + sm[1] + sm[2] + sm[3];
  float SS = sm[4] + sm[5] + sm[6] + sm[7];
  float mean = S * (1.0f / 1024.0f);
  float var = SS * (1.0f / 1024.0f) - mean * mean;
  float rstd = rsqrtf(var + 1e-5f);
#pragma unroll
  for (int j = 0; j < 4; j++) {
    int c = tid + j * 256;
    float o = (v[j] - mean) * rstd * g[c] + be[c];
    xf[base + c] = o;
    if (xb) xb[base + c] = f2b(o);
  }
}

extern "C" void kernel_launch(void* const* d_in, const int* in_sizes, int n_in,
                              void* d_out, int out_size, void* d_ws, size_t ws_size,
                              hipStream_t stream) {
  (void)in_sizes; (void)n_in; (void)out_size; (void)ws_size;
  const float* tgt = (const float*)d_in[0];
  const float* mem = (const float*)d_in[1];
  const float* wq  = (const float*)d_in[2];
  const float* bq  = (const float*)d_in[3];
  const float* wk  = (const float*)d_in[4];
  const float* bk  = (const float*)d_in[5];
  const float* wv  = (const float*)d_in[6];
  const float* bv  = (const float*)d_in[7];
  const float* wo  = (const float*)d_in[8];
  const float* bo  = (const float*)d_in[9];
  const float* w1  = (const float*)d_in[10];
  const float* b1  = (const float*)d_in[11];
  const float* w2  = (const float*)d_in[12];
  const float* b2  = (const float*)d_in[13];
  const float* g1  = (const float*)d_in[14];
  const float* be1 = (const float*)d_in[15];
  const float* g2  = (const float*)d_in[16];
  const float* be2 = (const float*)d_in[17];
  float* out = (float*)d_out;

  char* ws = (char*)d_ws;
  size_t off = 0;
  auto take = [&](size_t bytes) { char* p = ws + off; off += bytes; return p; };
  const size_t MB = 1024 * 1024;
  u16* tgt_b = (u16*)take(8 * MB);    // [4096][1024] bf16
  u16* mem_b = (u16*)take(8 * MB);
  u16* wqT   = (u16*)take(2 * MB);    // [1024][1024]
  u16* wkvT  = (u16*)take(4 * MB);    // [2048][1024]: wk^T then wv^T
  u16* woT   = (u16*)take(2 * MB);
  u16* w1T   = (u16*)take(8 * MB);    // [4096][1024]
  u16* w2T   = (u16*)take(8 * MB);    // [1024][4096]
  u16* Qb    = (u16*)take(8 * MB);
  u16* Kb    = (u16*)take(8 * MB);
  u16* Vtb   = (u16*)take(8 * MB);    // [32][64][2048]
  u16* ctx   = (u16*)take(8 * MB);
  float* fp2   = (float*)take(32 * MB);  // FFN2 partials [2][4096][1024] fp32
  float* opj   = (float*)take(32 * MB);  // O-proj raw out [4096][1024] fp32
  float* xf  = (float*)take(16 * MB);
  u16* xb    = (u16*)take(8 * MB);
  u16* hbuf  = Qb;                    // [4096][4096] bf16 over Qb..ctx (dead after O-proj)

  // 1. converts + weight transposes (one launch)
  k_pre<<<20480, 256, 0, stream>>>(tgt, mem, wq, wk, wv, wo, w1, w2,
                                   tgt_b, mem_b, wqT, wkvT, woT, w1T, w2T);
  // 2. Q + KV projections (one launch, 768 blocks, V-transpose fused)
  k_qkv<<<768, 256, 0, stream>>>(tgt_b, mem_b, wqT, wkvT, bq, bk, bv,
                                 Qb, Kb, Vtb);
  // 3. attention, t-split -> 1024 blocks, 4 blk/CU, writes ctx directly
  k_attn<<<1024, 256, 0, stream>>>(Qb, Kb, Vtb, ctx);
  // 4. O-proj non-split raw -> opj (16 BK-64 iters)
  k_gemm<64, 128><<<dim3(8, 64, 1), 256, 0, stream>>>(
      ctx, woT, nullptr, nullptr, opj, nullptr,
      4096, 1024, 1024, 1024, 1.0f, 16);
  // 5. LN1 fused combine: y = opj + bo + tgt
  k_lnp<<<4096, 256, 0, stream>>>(opj, 1, bo, tgt, g1, be1, xf, xb);
  // 6. FFN1: relu(x @ w1 + b1) via 256^2 phase-split kernel, 256 blocks 1/CU
  k_g256<<<dim3(16, 16, 1), 512, 0, stream>>>(
      xb, w1T, b1, nullptr, hbuf, 4096, 4096, 1024, 1024, 1 | 2);
  // 7. FFN2 split-K=2 raw partials -> fp2, BK=64 (32 iters per z)
  k_gemm<64, 128><<<dim3(8, 64, 2), 256, 0, stream>>>(
      hbuf, w2T, nullptr, nullptr, fp2, nullptr,
      4096, 1024, 4096, 2048, 1.0f, 16);
  // 8. LN2 fused combine: y = fp2_0+fp2_1+b2+xf
  k_lnp<<<4096, 256, 0, stream>>>(fp2, 2, b2, xf, g2, be2, out, nullptr);
}

// Round 10
// 356.991 us; speedup vs baseline: 1.0434x; 1.0434x over previous
//
#include <hip/hip_runtime.h>

// Round 18: (a) revert R17's k_g256 FFN1 (regression ~+5us: boundary-drain
// forfeited T4's counted-vmcnt gain; 1 blk/CU had no overlap partner) ->
// back to k_gemm<128,128>. (b) k_attn VALU anomaly: VALUBusy=50% implies
// ~480cy VALU/wave-iter but the loop census is ~250cy — suspect __expf
// lowers to the multi-instruction ocml path, not native v_mul+v_exp.
// Replace with explicit f32 mul by log2(e) + inline-asm v_exp_f32 (2 ops,
// NO change to Q/K quantization unlike R11's failed variant; ~1ulp delta).

typedef unsigned short u16;
typedef __attribute__((ext_vector_type(8))) short bvec8;   // 8 bf16 (4 VGPRs)
typedef __attribute__((ext_vector_type(4))) float fvec4;
typedef __attribute__((ext_vector_type(4))) unsigned uvec4;

#define MFMA16(a, b, c) __builtin_amdgcn_mfma_f32_16x16x32_bf16((a), (b), (c), 0, 0, 0)
#define LOG2E 1.44269504088896f

__device__ __forceinline__ u16 f2b(float f) {
  union { float f; unsigned u; } x; x.f = f;
  unsigned u = x.u;
  return (u16)((u + 0x7FFFu + ((u >> 16) & 1u)) >> 16);  // RNE
}
// bare 2^x via v_exp_f32 (native, 1 instr)
__device__ __forceinline__ float ex2(float x) {
  float r;
  asm("v_exp_f32 %0, %1" : "=v"(r) : "v"(x));
  return r;
}
// packed f32x2 -> bf16x2 (RNE), dst.lo = lo, dst.hi = hi
__device__ __forceinline__ unsigned cvtpk(float lo, float hi) {
  unsigned r;
  asm("v_cvt_pk_bf16_f32 %0, %1, %2" : "=v"(r) : "v"(lo), "v"(hi));
  return r;
}
// in-place cross-lane swaps (gfx950): 32 = swap halves across lane^32 axis,
// 16 = swap odd 16-rows of a with even 16-rows of b (lane^16 axis)
#define PLSWAP32(a, b) asm("v_permlane32_swap_b32 %0, %1" : "+v"(a), "+v"(b))
#define PLSWAP16(a, b) asm("v_permlane16_swap_b32 %0, %1" : "+v"(a), "+v"(b))

// async global->LDS, 16B/lane; LDS dest = wave-uniform base + lane*16
__device__ __forceinline__ void gl_lds16(const u16* g, u16* lds) {
  __builtin_amdgcn_global_load_lds(
      (const __attribute__((address_space(1))) void*)g,
      (__attribute__((address_space(3))) void*)lds, 16, 0, 0);
}

// ------- merged prep: fp32->bf16 converts (blocks 0..8191) + all weight
// ------- transposes W[K][N] -> WT[N][K] bf16 (blocks 8192..20479) ----------
__global__ __launch_bounds__(256) void k_pre(
    const float* __restrict__ tgt, const float* __restrict__ mem,
    const float* __restrict__ wq, const float* __restrict__ wk,
    const float* __restrict__ wv, const float* __restrict__ wo,
    const float* __restrict__ w1, const float* __restrict__ w2,
    u16* __restrict__ tgt_b, u16* __restrict__ mem_b,
    u16* __restrict__ wqT, u16* __restrict__ wkvT, u16* __restrict__ woT,
    u16* __restrict__ w1T, u16* __restrict__ w2T) {
  __shared__ float t[32][33];
  int bb = blockIdx.x;
  if (bb < 8192) {  // activation converts
    const float* in = (bb < 4096) ? tgt : mem;
    u16* outp = (bb < 4096) ? tgt_b : mem_b;
    int i = (bb & 4095) * 256 + threadIdx.x;
    float4 v = ((const float4*)in)[i];
    ushort4 o;
    o.x = f2b(v.x); o.y = f2b(v.y); o.z = f2b(v.z); o.w = f2b(v.w);
    ((ushort4*)outp)[i] = o;
    return;
  }
  int b = bb - 8192;
  const float* W; u16* WT; int K, N, bx, by;
  if (b < 4096) {            // wq/wk/wv/wo: 1024x1024, 1024 tiles each
    int m = b >> 10, tt = b & 1023;
    bx = tt & 31; by = tt >> 5; K = 1024; N = 1024;
    W = (m == 0) ? wq : (m == 1) ? wk : (m == 2) ? wv : wo;
    WT = (m == 0) ? wqT : (m == 1) ? wkvT : (m == 2) ? wkvT + 1024 * 1024 : woT;
  } else if (b < 8192) {     // w1: K=1024, N=4096
    int tt = b - 4096; bx = tt & 127; by = tt >> 7; K = 1024; N = 4096;
    W = w1; WT = w1T;
  } else {                   // w2: K=4096, N=1024
    int tt = b - 8192; bx = tt & 31; by = tt >> 5; K = 4096; N = 1024;
    W = w2; WT = w2T;
  }
  int tx = threadIdx.x & 31, ty = threadIdx.x >> 5;
  int n0 = bx * 32, k0 = by * 32;
#pragma unroll
  for (int i = 0; i < 4; i++)
    t[ty + i * 8][tx] = W[(size_t)(k0 + ty + i * 8) * N + n0 + tx];
  __syncthreads();
#pragma unroll
  for (int i = 0; i < 4; i++)
    WT[(size_t)(n0 + ty + i * 8) * K + k0 + tx] = f2b(t[tx][ty + i * 8]);
}

// ------- merged Q-proj + KV-proj, 128x128 tiles, BK=64, V-transpose fused ----
__global__ __launch_bounds__(256, 4) void k_qkv(
    const u16* __restrict__ tgt_b, const u16* __restrict__ mem_b,
    const u16* __restrict__ wqT, const u16* __restrict__ wkvT,
    const float* __restrict__ bq, const float* __restrict__ bk,
    const float* __restrict__ bv,
    u16* __restrict__ Qb, u16* __restrict__ Kb, u16* __restrict__ Vtb) {
  __shared__ u16 S[256 * 64];
  const int tid = threadIdx.x, w = tid >> 6, lane = tid & 63;
  const int q = lane >> 4, l = lane & 15;
  const bool isQ = blockIdx.x < 256;
  const int pq = isQ ? blockIdx.x : blockIdx.x - 256;
  const int lx = (pq >> 3) & (isQ ? 7 : 15);
  const int ly = (pq & 7) + ((pq >> (isQ ? 6 : 7)) << 3);
  const int m0 = ly * 128, n0 = lx * 128;
  const u16* A = isQ ? tgt_b : mem_b;
  const u16* BT = isQ ? wqT : wkvT;
  const int wm = (w >> 1) * 64, wn = (w & 1) * 64;
  const int rowin = lane >> 3, grp = lane & 7;
  const int gcol = ((grp + rowin) & 7) * 8;
  const int kc0 = ((q + 8 - (l & 7)) & 7) * 8;
  const int kc1 = ((q + 12 - (l & 7)) & 7) * 8;
  const u16* gp[8];
  u16* lp[8];
#pragma unroll
  for (int c = 0; c < 8; c++) {
    int r0 = (w * 8 + c) * 8;
    gp[c] = (r0 < 128) ? A + (size_t)(m0 + r0 + rowin) * 1024 + gcol
                       : BT + (size_t)(n0 + r0 - 128 + rowin) * 1024 + gcol;
    lp[c] = &S[r0 * 64];
  }
  fvec4 acc[4][4] = {};
#pragma unroll 1
  for (int k0 = 0; k0 < 1024; k0 += 64) {
#pragma unroll
    for (int c = 0; c < 8; c++) gl_lds16(gp[c] + k0, lp[c]);
    __syncthreads();
#pragma unroll
    for (int kh = 0; kh < 2; kh++) {
      const int kc = kh ? kc1 : kc0;
      bvec8 af[4], bf[4];
#pragma unroll
      for (int i = 0; i < 4; i++) {
        af[i] = *(const bvec8*)&S[(wm + 16 * i + l) * 64 + kc];
        bf[i] = *(const bvec8*)&S[(128 + wn + 16 * i + l) * 64 + kc];
      }
#pragma unroll
      for (int i = 0; i < 4; i++)
#pragma unroll
        for (int j = 0; j < 4; j++)
          acc[i][j] = MFMA16(af[i], bf[j], acc[i][j]);
    }
    __syncthreads();
  }
#pragma unroll
  for (int mi = 0; mi < 4; mi++)
#pragma unroll
    for (int ni = 0; ni < 4; ni++) {
      int row = m0 + wm + mi * 16 + q * 4;
      int col = n0 + wn + ni * 16 + l;
      if (isQ) {
        float bvv = bq[col];
#pragma unroll
        for (int r = 0; r < 4; r++)
          Qb[(size_t)(row + r) * 1024 + col] = f2b((acc[mi][ni][r] + bvv) * 0.125f);
      } else if (col < 1024) {
        float bvv = bk[col];
#pragma unroll
        for (int r = 0; r < 4; r++)
          Kb[(size_t)(row + r) * 1024 + col] = f2b(acc[mi][ni][r] + bvv);
      } else {
        int vcol = col - 1024;
        float bvv = bv[vcol];
        int b = row >> 11, s = row & 2047;
        int h = vcol >> 6, d = vcol & 63;
        ushort4 o;
        o.x = f2b(acc[mi][ni][0] + bvv);
        o.y = f2b(acc[mi][ni][1] + bvv);
        o.z = f2b(acc[mi][ni][2] + bvv);
        o.w = f2b(acc[mi][ni][3] + bvv);
        *(ushort4*)&Vtb[((size_t)(b * 16 + h) * 64 + d) * 2048 + s] = o;
      }
    }
}

// ---------------- templated MFMA GEMM: C[M][N] = A[M][K] @ BT[N][K]^T --------
// Tile TM x TN (2x2 wave grid), BK=64, global_load_lds w=16, &7-rotation
// swizzle. Split-K via gridDim.z. XCD-locality remap: p%8 == ly&7.
// flags: 1=relu, 2=bf16 outB, 4=fp32 outF, 8=add resid, 16=raw split-K partial.
template <int TM, int TN>
__global__ __launch_bounds__(256, 4) void k_gemm(
    const u16* __restrict__ A, const u16* __restrict__ BT,
    const float* __restrict__ bias, const float* __restrict__ resid,
    float* __restrict__ outF, u16* __restrict__ outB,
    int M, int N, int Kstride, int Klen, float scale, int flags) {
  constexpr int WM = TM / 2, WN = TN / 2;
  constexpr int MI = WM / 16, NI = WN / 16;
  constexpr int NCALL = (TM + TN) / 32;
  __shared__ u16 S[(TM + TN) * 64];
  const int tid = threadIdx.x, w = tid >> 6, lane = tid & 63;
  const int q = lane >> 4, l = lane & 15;
  const int nx = gridDim.x, nyh = gridDim.y >> 3;
  const int p = blockIdx.x + nx * (blockIdx.y + gridDim.y * blockIdx.z);
  const int q8 = p >> 3;
  const int lx = q8 & (nx - 1);
  const int t = q8 >> __builtin_ctz(nx);
  const int ly = (p & 7) + ((t & (nyh - 1)) << 3);
  const int lz = t >> __builtin_ctz(nyh);
  const int m0 = ly * TM, n0 = lx * TN;
  const int kbeg = lz * Klen;
  const int wm = (w >> 1) * WM, wn = (w & 1) * WN;
  const int rowin = lane >> 3, grp = lane & 7;
  const int gcol = ((grp + rowin) & 7) * 8;
  const int kc0 = ((q + 8 - (l & 7)) & 7) * 8;
  const int kc1 = ((q + 12 - (l & 7)) & 7) * 8;
  const u16* gp[NCALL];
  u16* lp[NCALL];
#pragma unroll
  for (int c = 0; c < NCALL; c++) {
    int r0 = (w * NCALL + c) * 8;
    gp[c] = (r0 < TM) ? A + (size_t)(m0 + r0 + rowin) * Kstride + kbeg + gcol
                      : BT + (size_t)(n0 + r0 - TM + rowin) * Kstride + kbeg + gcol;
    lp[c] = &S[r0 * 64];
  }
  fvec4 acc[MI][NI] = {};
#pragma unroll 1
  for (int k0 = 0; k0 < Klen; k0 += 64) {
#pragma unroll
    for (int c = 0; c < NCALL; c++) gl_lds16(gp[c] + k0, lp[c]);
    __syncthreads();
#pragma unroll
    for (int kh = 0; kh < 2; kh++) {
      const int kc = kh ? kc1 : kc0;
      bvec8 af[MI], bf[NI];
#pragma unroll
      for (int i = 0; i < MI; i++)
        af[i] = *(const bvec8*)&S[(wm + 16 * i + l) * 64 + kc];
#pragma unroll
      for (int j = 0; j < NI; j++)
        bf[j] = *(const bvec8*)&S[(TM + wn + 16 * j + l) * 64 + kc];
#pragma unroll
      for (int i = 0; i < MI; i++)
#pragma unroll
        for (int j = 0; j < NI; j++)
          acc[i][j] = MFMA16(af[i], bf[j], acc[i][j]);
    }
    __syncthreads();
  }
  if (flags & 16) {
    float* po = outF + (size_t)lz * M * N;
#pragma unroll
    for (int mi = 0; mi < MI; mi++)
#pragma unroll
      for (int ni = 0; ni < NI; ni++) {
        int row = m0 + wm + mi * 16 + q * 4;
        int col = n0 + wn + ni * 16 + l;
#pragma unroll
        for (int r = 0; r < 4; r++)
          po[(size_t)(row + r) * N + col] = acc[mi][ni][r];
      }
    return;
  }
#pragma unroll
  for (int mi = 0; mi < MI; mi++)
#pragma unroll
    for (int ni = 0; ni < NI; ni++) {
      int row = m0 + wm + mi * 16 + q * 4;
      int col = n0 + wn + ni * 16 + l;
      float bvv = bias[col];
#pragma unroll
      for (int r = 0; r < 4; r++) {
        float v = (acc[mi][ni][r] + bvv) * scale;
        if (flags & 1) v = fmaxf(v, 0.0f);
        size_t idx = (size_t)(row + r) * N + col;
        if (flags & 8) v += resid[idx];
        if (flags & 2) outB[idx] = f2b(v);
        if (flags & 4) outF[idx] = v;
      }
    }
}

// ---------------- block-cooperative no-max flash attention, t-split ----------
// grid 1024: 32 bh x 32 t-chunks (64 t each; wave w owns t = tb*64+w*16+l).
// Each block loops the FULL S=2048 -> l complete in-kernel; epilogue
// normalizes o/l and writes bf16 ctx directly. Swapped QK^T -> S^T in regs;
// P = 2^(S*log2e) via explicit v_mul + native v_exp_f32 (2 VALU ops — avoids
// any heavyweight __expf lowering; Q/K quantization untouched).
// cvt_pk + permlane butterfly -> PV B-frag; l via ones-MFMA; K/V double-
// buffered in LDS, one barrier per s-tile; setprio on MFMA clusters (T5).
__global__ __launch_bounds__(256, 4) void k_attn(
    const u16* __restrict__ Q, const u16* __restrict__ Kb,
    const u16* __restrict__ Vt, u16* __restrict__ ctx) {
  __shared__ u16 Ks[2][64 * 64];
  __shared__ u16 Vs[2][64 * 64];
  const int tid = threadIdx.x, w = tid >> 6, lane = tid & 63;
  const int q = lane >> 4, l = lane & 15;
  const int bx = blockIdx.x;
  const int blk = (bx & 7) * 128 + (bx >> 3);
  const int bh = blk >> 5, tb = blk & 31;
  const int b = bh >> 4, h = bh & 15;
  const int t0 = tb * 64 + w * 16;
  const u16* Qp = Q + (size_t)(b * 2048 + t0) * 1024 + h * 64;
  const u16* Kp = Kb + (size_t)(b * 2048) * 1024 + h * 64;
  const u16* Vp = Vt + (size_t)bh * 64 * 2048;
  const int rowin = lane >> 3, grp = lane & 7;
  const int gcol = ((grp + rowin) & 7) * 8;
  const int kc0 = ((q + 8 - (l & 7)) & 7) * 8;
  const int kc1 = ((q + 12 - (l & 7)) & 7) * 8;
  bvec8 aQ[2];
#pragma unroll
  for (int kh = 0; kh < 2; kh++)
    aQ[kh] = *(const bvec8*)&Qp[(size_t)l * 1024 + kh * 32 + q * 8];
  const short oneb = (short)0x3F80;
  const bvec8 aOne = {oneb, oneb, oneb, oneb, oneb, oneb, oneb, oneb};
  fvec4 o[4] = {};
  fvec4 lacc = {};
  auto stage = [&](int bb, int sv) {
    gl_lds16(Kp + (size_t)(sv + w * 8 + rowin) * 1024 + gcol, &Ks[bb][(w * 8) * 64]);
    gl_lds16(Kp + (size_t)(sv + 32 + w * 8 + rowin) * 1024 + gcol, &Ks[bb][(32 + w * 8) * 64]);
    gl_lds16(Vp + (size_t)(w * 8 + rowin) * 2048 + sv + gcol, &Vs[bb][(w * 8) * 64]);
    gl_lds16(Vp + (size_t)(32 + w * 8 + rowin) * 2048 + sv + gcol, &Vs[bb][(32 + w * 8) * 64]);
  };
  stage(0, 0);
  int cur = 0;
#pragma unroll 1
  for (int s0 = 0; s0 < 2048; s0 += 64) {
    __syncthreads();
    if (s0 + 64 < 2048) stage(cur ^ 1, s0 + 64);
    const u16* KsC = Ks[cur];
    const u16* VsC = Vs[cur];
    unsigned pw[4][2];
    __builtin_amdgcn_s_setprio(1);
#pragma unroll
    for (int ss = 0; ss < 4; ss++) {
      const int ro = (ss * 16 + l) * 64;
      bvec8 kf0 = *(const bvec8*)&KsC[ro + kc0];
      bvec8 kf1 = *(const bvec8*)&KsC[ro + kc1];
      fvec4 sc = {0.f, 0.f, 0.f, 0.f};
      sc = MFMA16(kf0, aQ[0], sc);
      sc = MFMA16(kf1, aQ[1], sc);
      float p0 = ex2(sc[0] * LOG2E), p1 = ex2(sc[1] * LOG2E);
      float p2 = ex2(sc[2] * LOG2E), p3 = ex2(sc[3] * LOG2E);
      pw[ss][0] = cvtpk(p0, p1);
      pw[ss][1] = cvtpk(p2, p3);
    }
    __builtin_amdgcn_s_setprio(0);
#pragma unroll
    for (int b4 = 0; b4 < 2; b4++)
#pragma unroll
      for (int r2 = 0; r2 < 2; r2++) {
        PLSWAP32(pw[2 * b4][r2], pw[2 * b4 + 1][r2]);
        PLSWAP16(pw[2 * b4][r2], pw[2 * b4 + 1][r2]);
      }
    bvec8 bP[2];
#pragma unroll
    for (int kh = 0; kh < 2; kh++) {
      uvec4 t = {pw[2 * kh][0], pw[2 * kh][1],
                 pw[2 * kh + 1][0], pw[2 * kh + 1][1]};
      bP[kh] = __builtin_bit_cast(bvec8, t);
    }
    bvec8 bV[4][2];
#pragma unroll
    for (int dt = 0; dt < 4; dt++) {
      const int ro = (dt * 16 + l) * 64;
      bV[dt][0] = *(const bvec8*)&VsC[ro + kc0];
      bV[dt][1] = *(const bvec8*)&VsC[ro + kc1];
    }
    __builtin_amdgcn_s_setprio(1);
#pragma unroll
    for (int dt = 0; dt < 4; dt++) {
      o[dt] = MFMA16(bV[dt][0], bP[0], o[dt]);
      o[dt] = MFMA16(bV[dt][1], bP[1], o[dt]);
    }
    lacc = MFMA16(aOne, bP[0], lacc);
    lacc = MFMA16(aOne, bP[1], lacc);
    __builtin_amdgcn_s_setprio(0);
    cur ^= 1;
  }
  const float inv = 1.0f / lacc[0];
  u16* cp = ctx + (size_t)(b * 2048 + t0 + l) * 1024 + h * 64;
#pragma unroll
  for (int dt = 0; dt < 4; dt++) {
    ushort4 o4;
    o4.x = f2b(o[dt][0] * inv);
    o4.y = f2b(o[dt][1] * inv);
    o4.z = f2b(o[dt][2] * inv);
    o4.w = f2b(o[dt][3] * inv);
    *(ushort4*)&cp[dt * 16 + q * 4] = o4;
  }
}

// ---- LayerNorm over dim 1024, fused split-K combine: y = Σparts+bias+res ----
__global__ __launch_bounds__(256) void k_lnp(
    const float* __restrict__ parts, int nparts,
    const float* __restrict__ bias, const float* __restrict__ resid,
    const float* __restrict__ g, const float* __restrict__ be,
    float* __restrict__ xf, u16* __restrict__ xb) {
  __shared__ float sm[8];
  int row = blockIdx.x, tid = threadIdx.x;
  size_t base = (size_t)row * 1024;
  const size_t pstride = (size_t)4096 * 1024;
  float v[4], s = 0.f, ss = 0.f;
#pragma unroll
  for (int j = 0; j < 4; j++) {
    int c = tid + j * 256;
    float acc = bias[c] + resid[base + c];
    for (int z = 0; z < nparts; z++) acc += parts[z * pstride + base + c];
    v[j] = acc;
    s += acc; ss += acc * acc;
  }
#pragma unroll
  for (int off = 32; off; off >>= 1) {
    s += __shfl_down(s, off, 64);
    ss += __shfl_down(ss, off, 64);
  }
  int w = tid >> 6;
  if ((tid & 63) == 0) { sm[w] = s; sm[4 + w] = ss; }
  __syncthreads();
  float S = sm[0] + sm[1] + sm[2] + sm[3];
  float SS = sm[4] + sm[5] + sm[6] + sm[7];
  float mean = S * (1.0f / 1024.0f);
  float var = SS * (1.0f / 1024.0f) - mean * mean;
  float rstd = rsqrtf(var + 1e-5f);
#pragma unroll
  for (int j = 0; j < 4; j++) {
    int c = tid + j * 256;
    float o = (v[j] - mean) * rstd * g[c] + be[c];
    xf[base + c] = o;
    if (xb) xb[base + c] = f2b(o);
  }
}

extern "C" void kernel_launch(void* const* d_in, const int* in_sizes, int n_in,
                              void* d_out, int out_size, void* d_ws, size_t ws_size,
                              hipStream_t stream) {
  (void)in_sizes; (void)n_in; (void)out_size; (void)ws_size;
  const float* tgt = (const float*)d_in[0];
  const float* mem = (const float*)d_in[1];
  const float* wq  = (const float*)d_in[2];
  const float* bq  = (const float*)d_in[3];
  const float* wk  = (const float*)d_in[4];
  const float* bk  = (const float*)d_in[5];
  const float* wv  = (const float*)d_in[6];
  const float* bv  = (const float*)d_in[7];
  const float* wo  = (const float*)d_in[8];
  const float* bo  = (const float*)d_in[9];
  const float* w1  = (const float*)d_in[10];
  const float* b1  = (const float*)d_in[11];
  const float* w2  = (const float*)d_in[12];
  const float* b2  = (const float*)d_in[13];
  const float* g1  = (const float*)d_in[14];
  const float* be1 = (const float*)d_in[15];
  const float* g2  = (const float*)d_in[16];
  const float* be2 = (const float*)d_in[17];
  float* out = (float*)d_out;

  char* ws = (char*)d_ws;
  size_t off = 0;
  auto take = [&](size_t bytes) { char* p = ws + off; off += bytes; return p; };
  const size_t MB = 1024 * 1024;
  u16* tgt_b = (u16*)take(8 * MB);    // [4096][1024] bf16
  u16* mem_b = (u16*)take(8 * MB);
  u16* wqT   = (u16*)take(2 * MB);    // [1024][1024]
  u16* wkvT  = (u16*)take(4 * MB);    // [2048][1024]: wk^T then wv^T
  u16* woT   = (u16*)take(2 * MB);
  u16* w1T   = (u16*)take(8 * MB);    // [4096][1024]
  u16* w2T   = (u16*)take(8 * MB);    // [1024][4096]
  u16* Qb    = (u16*)take(8 * MB);
  u16* Kb    = (u16*)take(8 * MB);
  u16* Vtb   = (u16*)take(8 * MB);    // [32][64][2048]
  u16* ctx   = (u16*)take(8 * MB);
  float* fp2   = (float*)take(32 * MB);  // FFN2 partials [2][4096][1024] fp32
  float* opj   = (float*)take(32 * MB);  // O-proj raw out [4096][1024] fp32
  float* xf  = (float*)take(16 * MB);
  u16* xb    = (u16*)take(8 * MB);
  u16* hbuf  = Qb;                    // [4096][4096] bf16 over Qb..ctx (dead after O-proj)

  // 1. converts + weight transposes (one launch)
  k_pre<<<20480, 256, 0, stream>>>(tgt, mem, wq, wk, wv, wo, w1, w2,
                                   tgt_b, mem_b, wqT, wkvT, woT, w1T, w2T);
  // 2. Q + KV projections (one launch, 768 blocks, V-transpose fused)
  k_qkv<<<768, 256, 0, stream>>>(tgt_b, mem_b, wqT, wkvT, bq, bk, bv,
                                 Qb, Kb, Vtb);
  // 3. attention, t-split -> 1024 blocks, 4 blk/CU, writes ctx directly
  k_attn<<<1024, 256, 0, stream>>>(Qb, Kb, Vtb, ctx);
  // 4. O-proj non-split raw -> opj (16 BK-64 iters)
  k_gemm<64, 128><<<dim3(8, 64, 1), 256, 0, stream>>>(
      ctx, woT, nullptr, nullptr, opj, nullptr,
      4096, 1024, 1024, 1024, 1.0f, 16);
  // 5. LN1 fused combine: y = opj + bo + tgt
  k_lnp<<<4096, 256, 0, stream>>>(opj, 1, bo, tgt, g1, be1, xf, xb);
  // 6. FFN1: relu(x @ w1 + b1), 128x128, 1024 blocks, BK=64
  k_gemm<128, 128><<<dim3(32, 32), 256, 0, stream>>>(
      xb, w1T, b1, nullptr, nullptr, hbuf,
      4096, 4096, 1024, 1024, 1.0f, 1 | 2);
  // 7. FFN2 split-K=2 raw partials -> fp2, BK=64 (32 iters per z)
  k_gemm<64, 128><<<dim3(8, 64, 2), 256, 0, stream>>>(
      hbuf, w2T, nullptr, nullptr, fp2, nullptr,
      4096, 1024, 4096, 2048, 1.0f, 16);
  // 8. LN2 fused combine: y = fp2_0+fp2_1+b2+xf
  k_lnp<<<4096, 256, 0, stream>>>(fp2, 2, b2, xf, g2, be2, out, nullptr);
}